// Round 16
// baseline (322.078 us; speedup 1.0000x reference)
//
#include <hip/hip_runtime.h>
#include <hip/hip_bf16.h>
#include <stdint.h>

namespace {

constexpr int MTOT = 8192;
constexpr int NTOT = 4096;
constexpr int KTOT = 4096;

constexpr int CONV_BLOCKS = (MTOT * KTOT / 8) / 256;   // 16384
constexpr int GENW_BLOCKS = (NTOT * KTOT / 8) / 256;   // 8192

typedef __attribute__((ext_vector_type(8))) short bf16x8;
typedef __attribute__((ext_vector_type(4))) float f32x4;

__device__ inline unsigned short to_bf16(float f) {
    union { float f; uint32_t u; } v; v.f = f;
    return (unsigned short)((v.u + 0x7FFFu + ((v.u >> 16) & 1u)) >> 16);
}

// ---- Kernel 1: merged prep (unchanged from r13/r15 best) ----
__global__ __launch_bounds__(256) void prep_kernel(const float* __restrict__ x,
                                                   const float* __restrict__ a,
                                                   const float* __restrict__ s,
                                                   unsigned short* __restrict__ xb,
                                                   unsigned short* __restrict__ wb) {
    if (blockIdx.x < CONV_BLOCKS) {
        int idx = blockIdx.x * 256 + threadIdx.x;
        const f32x4* xv = reinterpret_cast<const f32x4*>(x);
        f32x4 v0 = xv[2 * idx];
        f32x4 v1 = xv[2 * idx + 1];
        union { bf16x8 v; unsigned short q[8]; } o;
        o.q[0] = to_bf16(v0.x); o.q[1] = to_bf16(v0.y);
        o.q[2] = to_bf16(v0.z); o.q[3] = to_bf16(v0.w);
        o.q[4] = to_bf16(v1.x); o.q[5] = to_bf16(v1.y);
        o.q[6] = to_bf16(v1.z); o.q[7] = to_bf16(v1.w);
        reinterpret_cast<bf16x8*>(xb)[idx] = o.v;
    } else {
        int idx = (blockIdx.x - CONV_BLOCKS) * 256 + threadIdx.x;
        int o  = idx >> 9;
        int i8 = idx & 511;
        int i0 = i8 * 8;
        int obig = o >> 9, orow = o & 511;
        int ibig = i0 >> 9, icol = i0 & 511;
        float acc[8];
#pragma unroll
        for (int j = 0; j < 8; ++j) acc[j] = 0.f;
#pragma unroll
        for (int b = 0; b < 8; ++b) {
            float av = a[b * 64 + obig * 8 + ibig];
            const f32x4* sv = reinterpret_cast<const f32x4*>(s + b * 512 * 512 + orow * 512 + icol);
            f32x4 s0 = sv[0], s1 = sv[1];
            acc[0] += av * s0.x; acc[1] += av * s0.y; acc[2] += av * s0.z; acc[3] += av * s0.w;
            acc[4] += av * s1.x; acc[5] += av * s1.y; acc[6] += av * s1.z; acc[7] += av * s1.w;
        }
        union { bf16x8 v; unsigned short q[8]; } ov;
#pragma unroll
        for (int j = 0; j < 8; ++j) ov.q[j] = to_bf16(acc[j]);
        reinterpret_cast<bf16x8*>(wb)[idx] = ov.v;
    }
}

// ---- Kernel 2: 8-phase derived-waits GEMM (m201 template port, attempt 3) ----
// 256x256 tile, K-tile=64, dbuf x row-half LDS [2][2][128][64], 8 waves with
// CONTIGUOUS 128x64 ownership (proven geometry). Phase = one wave quadrant
// (16 MFMA); 12/4/8/0 ds_reads at ph1-4; one half-tile (2 gloads) staged per
// phase in last-reader order; vmcnt(4) at ph4/ph8 only (forces halves staged
// >=2 phases ago; every half read 4-6 phases after its stage).
__global__ __launch_bounds__(512, 2)
void gemm_bt_kernel(const unsigned short* __restrict__ A,
                    const unsigned short* __restrict__ B,
                    float* __restrict__ C) {
    __shared__ __align__(16) unsigned short As[2][2][128][64];
    __shared__ __align__(16) unsigned short Bs[2][2][128][64];

    int bid = blockIdx.x;
    int swz = (bid & 7) * 64 + (bid >> 3);
    int bm = swz >> 4;
    int bn = swz & 15;

    int tid  = threadIdx.x;
    int wid  = tid >> 6;
    int lane = tid & 63;
    int wm = wid >> 2, wn = wid & 3;   // wave tile 128x64: rows wm*128, cols wn*64

    // staging: lane l writes LDS row l>>3 (+sg), unit l&7; source pre-swizzled
    int sr = lane >> 3;                 // 0..7
    int su = (lane & 7) ^ sr;           // logical unit at physical (lane&7)
    const size_t K = (size_t)KTOT;
    const unsigned short* Ag = A + (size_t)(bm * 256 + wid * 16 + sr) * K + su * 8;
    const unsigned short* Bg = B + (size_t)(bn * 256 + wid * 16 + sr) * K + su * 8;

    auto SA = [&](int buf, int h, int tile) {
        const unsigned short* src = Ag + (size_t)(h * 128) * K + tile * 64;
        __builtin_amdgcn_global_load_lds(
            (const __attribute__((address_space(1))) void*)src,
            (__attribute__((address_space(3))) void*)&As[buf][h][wid * 16][0], 16, 0, 0);
        __builtin_amdgcn_global_load_lds(
            (const __attribute__((address_space(1))) void*)(src + 8 * K),
            (__attribute__((address_space(3))) void*)&As[buf][h][wid * 16 + 8][0], 16, 0, 0);
    };
    auto SB = [&](int buf, int h, int tile) {
        const unsigned short* src = Bg + (size_t)(h * 128) * K + tile * 64;
        __builtin_amdgcn_global_load_lds(
            (const __attribute__((address_space(1))) void*)src,
            (__attribute__((address_space(3))) void*)&Bs[buf][h][wid * 16][0], 16, 0, 0);
        __builtin_amdgcn_global_load_lds(
            (const __attribute__((address_space(1))) void*)(src + 8 * K),
            (__attribute__((address_space(3))) void*)&Bs[buf][h][wid * 16 + 8][0], 16, 0, 0);
    };

    // fragment reads: physical unit = (ks*4 + kq) ^ (row&7); row&7 == rl&7
    int rl = lane & 15;
    int kq = lane >> 4;
    int rx = rl & 7;
    auto LDA = [&](int buf, int mq, int i, int ks) -> bf16x8 {
        int row = mq * 64 + i * 16 + rl;
        int u = (ks * 4 + kq) ^ rx;
        return *reinterpret_cast<const bf16x8*>(&As[buf][wm][row][u * 8]);
    };
    auto LDB = [&](int buf, int nq, int gi, int ks) -> bf16x8 {
        int row = (wn & 1) * 64 + nq * 32 + gi * 16 + rl;
        int u = (ks * 4 + kq) ^ rx;
        return *reinterpret_cast<const bf16x8*>(&Bs[buf][wn >> 1][row][u * 8]);
    };

    f32x4 acc[8][4];
#pragma unroll
    for (int m = 0; m < 8; ++m)
#pragma unroll
        for (int n = 0; n < 4; ++n) acc[m][n] = (f32x4)0.f;

    bf16x8 af[4][2], b0[2][2], b1[2][2];

    auto MM = [&](int mq, int nq, bf16x8 (&bq)[2][2]) {
        __builtin_amdgcn_s_setprio(1);
#pragma unroll
        for (int i = 0; i < 4; ++i)
#pragma unroll
            for (int gi = 0; gi < 2; ++gi)
#pragma unroll
                for (int ks = 0; ks < 2; ++ks)
                    acc[mq * 4 + i][nq * 2 + gi] = __builtin_amdgcn_mfma_f32_16x16x32_bf16(
                        af[i][ks], bq[gi][ks], acc[mq * 4 + i][nq * 2 + gi], 0, 0, 0);
        __builtin_amdgcn_s_setprio(0);
        __builtin_amdgcn_s_barrier();
    };

    // ---- prologue: tile0 all halves + tile1 B halves (12 loads) ----
    SB(0, 0, 0); SB(0, 1, 0); SA(0, 0, 0); SA(0, 1, 0);
    SB(1, 0, 1); SB(1, 1, 1);
    asm volatile("s_waitcnt vmcnt(0)" ::: "memory");
    __builtin_amdgcn_s_barrier();

    // ---- main loop: 32 iters x 2 K64-tiles, 8 phases each ----
    for (int j = 0; j < 32; ++j) {
        const int t1 = 2 * j + 1;                       // buf1 tile (read ph5-8)
        const int te = (2 * j + 2 > 62) ? 62 : 2 * j + 2;   // buf0 next
        const int to = (2 * j + 3 > 63) ? 63 : 2 * j + 3;   // buf1 next

        // PH1 (buf0, mq0 x nq0): 12 reads; stage buf1.A-h0 (t1)
#pragma unroll
        for (int i = 0; i < 4; ++i) { af[i][0] = LDA(0, 0, i, 0); af[i][1] = LDA(0, 0, i, 1); }
#pragma unroll
        for (int gi = 0; gi < 2; ++gi) { b0[gi][0] = LDB(0, 0, gi, 0); b0[gi][1] = LDB(0, 0, gi, 1); }
        SA(1, 0, t1);
        asm volatile("s_waitcnt lgkmcnt(8)" ::: "memory");
        __builtin_amdgcn_s_barrier();
        asm volatile("s_waitcnt lgkmcnt(0)" ::: "memory");
        __builtin_amdgcn_sched_barrier(0);
        MM(0, 0, b0);

        // PH2 (mq0 x nq1): 4 reads (B nq1); stage buf1.A-h1 (t1)
#pragma unroll
        for (int gi = 0; gi < 2; ++gi) { b1[gi][0] = LDB(0, 1, gi, 0); b1[gi][1] = LDB(0, 1, gi, 1); }
        SA(1, 1, t1);
        __builtin_amdgcn_s_barrier();
        asm volatile("s_waitcnt lgkmcnt(0)" ::: "memory");
        __builtin_amdgcn_sched_barrier(0);
        MM(0, 1, b1);

        // PH3 (mq1 x nq0): 8 reads (A mq1); stage buf0.B-h0 (te)
#pragma unroll
        for (int i = 0; i < 4; ++i) { af[i][0] = LDA(0, 1, i, 0); af[i][1] = LDA(0, 1, i, 1); }
        SB(0, 0, te);
        __builtin_amdgcn_s_barrier();
        asm volatile("s_waitcnt lgkmcnt(0)" ::: "memory");
        __builtin_amdgcn_sched_barrier(0);
        MM(1, 0, b0);

        // PH4 (mq1 x nq1): 0 reads; stage buf0.B-h1 (te); GATE vmcnt(4)
        SB(0, 1, te);
        asm volatile("s_waitcnt vmcnt(4)" ::: "memory");
        __builtin_amdgcn_s_barrier();
        asm volatile("s_waitcnt lgkmcnt(0)" ::: "memory");
        __builtin_amdgcn_sched_barrier(0);
        MM(1, 1, b1);

        // PH5 (buf1, mq0 x nq0): 12 reads; stage buf0.A-h0 (te)
#pragma unroll
        for (int i = 0; i < 4; ++i) { af[i][0] = LDA(1, 0, i, 0); af[i][1] = LDA(1, 0, i, 1); }
#pragma unroll
        for (int gi = 0; gi < 2; ++gi) { b0[gi][0] = LDB(1, 0, gi, 0); b0[gi][1] = LDB(1, 0, gi, 1); }
        SA(0, 0, te);
        asm volatile("s_waitcnt lgkmcnt(8)" ::: "memory");
        __builtin_amdgcn_s_barrier();
        asm volatile("s_waitcnt lgkmcnt(0)" ::: "memory");
        __builtin_amdgcn_sched_barrier(0);
        MM(0, 0, b0);

        // PH6 (mq0 x nq1): 4 reads; stage buf0.A-h1 (te)
#pragma unroll
        for (int gi = 0; gi < 2; ++gi) { b1[gi][0] = LDB(1, 1, gi, 0); b1[gi][1] = LDB(1, 1, gi, 1); }
        SA(0, 1, te);
        __builtin_amdgcn_s_barrier();
        asm volatile("s_waitcnt lgkmcnt(0)" ::: "memory");
        __builtin_amdgcn_sched_barrier(0);
        MM(0, 1, b1);

        // PH7 (mq1 x nq0): 8 reads; stage buf1.B-h0 (to)
#pragma unroll
        for (int i = 0; i < 4; ++i) { af[i][0] = LDA(1, 1, i, 0); af[i][1] = LDA(1, 1, i, 1); }
        SB(1, 0, to);
        __builtin_amdgcn_s_barrier();
        asm volatile("s_waitcnt lgkmcnt(0)" ::: "memory");
        __builtin_amdgcn_sched_barrier(0);
        MM(1, 0, b0);

        // PH8 (mq1 x nq1): 0 reads; stage buf1.B-h1 (to); GATE vmcnt(4)
        SB(1, 1, to);
        asm volatile("s_waitcnt vmcnt(4)" ::: "memory");
        __builtin_amdgcn_s_barrier();
        asm volatile("s_waitcnt lgkmcnt(0)" ::: "memory");
        __builtin_amdgcn_sched_barrier(0);
        MM(1, 1, b1);
    }
    asm volatile("s_waitcnt vmcnt(0)" ::: "memory");

    // ---- C write: standard layout, col = lane&15, row = (lane>>4)*4 + jj ----
    int crow0 = bm * 256 + wm * 128 + (lane >> 4) * 4;
    int ccol0 = bn * 256 + wn * 64 + (lane & 15);
#pragma unroll
    for (int m = 0; m < 8; ++m)
#pragma unroll
        for (int n = 0; n < 4; ++n)
#pragma unroll
            for (int jj = 0; jj < 4; ++jj) {
                size_t r = (size_t)(crow0 + m * 16 + jj);
                size_t c = (size_t)(ccol0 + n * 16);
                C[r * NTOT + c] = acc[m][n][jj];
            }
}

} // anonymous namespace

extern "C" void kernel_launch(void* const* d_in, const int* in_sizes, int n_in,
                              void* d_out, int out_size, void* d_ws, size_t ws_size,
                              hipStream_t stream) {
    const float* x = (const float*)d_in[0];
    const float* a = (const float*)d_in[1];
    const float* s = (const float*)d_in[2];
    float* out = (float*)d_out;

    unsigned short* xb = (unsigned short*)d_ws;
    unsigned short* wb = xb + (size_t)MTOT * KTOT;

    prep_kernel<<<CONV_BLOCKS + GENW_BLOCKS, 256, 0, stream>>>(x, a, s, xb, wb);
    gemm_bt_kernel<<<(MTOT / 256) * (NTOT / 256), 512, 0, stream>>>(xb, wb, out);
}

// Round 17
// 289.562 us; speedup vs baseline: 1.1123x; 1.1123x over previous
//
#include <hip/hip_runtime.h>
#include <hip/hip_bf16.h>
#include <stdint.h>

namespace {

constexpr int MTOT = 8192;   // 4 * 2048 rows of x
constexpr int NTOT = 4096;   // OUT_DIM
constexpr int KTOT = 4096;   // IN_DIM

constexpr int BM = 256, BN = 256, BK = 32;
constexpr int NT = KTOT / BK;     // 128 K-tiles

constexpr int CONV_BLOCKS = (MTOT * KTOT / 8) / 256;   // 16384
constexpr int GENW_BLOCKS = (NTOT * KTOT / 8) / 256;   // 8192

typedef __attribute__((ext_vector_type(8))) short bf16x8;
typedef __attribute__((ext_vector_type(4))) float f32x4;

__device__ inline unsigned short to_bf16(float f) {
    union { float f; uint32_t u; } v; v.f = f;
    return (unsigned short)((v.u + 0x7FFFu + ((v.u >> 16) & 1u)) >> 16);
}

// ---- Kernel 1: merged prep. Blocks [0,16384): x fp32->bf16. Blocks
// [16384, 24576): W[o][i] = sum_b a[b][o/512][i/512]*s[b][o%512][i%512].
// Block-uniform branch; both paths memory-bound and fully vectorized.
// (r14 lesson: nontemporal hints REGRESS — NT stores bypass L2 write
// combining and amplify HBM writes 131->170 MB. Plain loads/stores.)
__global__ __launch_bounds__(256) void prep_kernel(const float* __restrict__ x,
                                                   const float* __restrict__ a,
                                                   const float* __restrict__ s,
                                                   unsigned short* __restrict__ xb,
                                                   unsigned short* __restrict__ wb) {
    if (blockIdx.x < CONV_BLOCKS) {
        int idx = blockIdx.x * 256 + threadIdx.x;
        const f32x4* xv = reinterpret_cast<const f32x4*>(x);
        f32x4 v0 = xv[2 * idx];
        f32x4 v1 = xv[2 * idx + 1];
        union { bf16x8 v; unsigned short q[8]; } o;
        o.q[0] = to_bf16(v0.x); o.q[1] = to_bf16(v0.y);
        o.q[2] = to_bf16(v0.z); o.q[3] = to_bf16(v0.w);
        o.q[4] = to_bf16(v1.x); o.q[5] = to_bf16(v1.y);
        o.q[6] = to_bf16(v1.z); o.q[7] = to_bf16(v1.w);
        reinterpret_cast<bf16x8*>(xb)[idx] = o.v;
    } else {
        int idx = (blockIdx.x - CONV_BLOCKS) * 256 + threadIdx.x;
        int o  = idx >> 9;
        int i8 = idx & 511;
        int i0 = i8 * 8;
        int obig = o >> 9, orow = o & 511;
        int ibig = i0 >> 9, icol = i0 & 511;

        float acc[8];
#pragma unroll
        for (int j = 0; j < 8; ++j) acc[j] = 0.f;
#pragma unroll
        for (int b = 0; b < 8; ++b) {
            float av = a[b * 64 + obig * 8 + ibig];
            const f32x4* sv = reinterpret_cast<const f32x4*>(s + b * 512 * 512 + orow * 512 + icol);
            f32x4 s0 = sv[0], s1 = sv[1];
            acc[0] += av * s0.x; acc[1] += av * s0.y; acc[2] += av * s0.z; acc[3] += av * s0.w;
            acc[4] += av * s1.x; acc[5] += av * s1.y; acc[6] += av * s1.z; acc[7] += av * s1.w;
        }
        union { bf16x8 v; unsigned short q[8]; } ov;
#pragma unroll
        for (int j = 0; j < 8; ++j) ov.q[j] = to_bf16(acc[j]);
        reinterpret_cast<bf16x8*>(wb)[idx] = ov.v;
    }
}

// ---- Kernel 2: C[m,n] = sum_k A[m,k] * B[n,k]  (r7/r13/r15 verified best) ----
// 256x256 tile, BK=32, 4-deep LDS ring, 8 waves 2Mx4N, XOR swizzle,
// register fragment double-buffer, ONE {vmcnt(4); s_barrier} per K-tile.
// Eleven schedule variants (r3-r12, r16) bracket 33-50% MfmaUtil; this
// structure is the verified optimum (251-258 us GEMM, ~1065 TF, 49% util).
__global__ __launch_bounds__(512, 2)
void gemm_bt_kernel(const unsigned short* __restrict__ A,
                    const unsigned short* __restrict__ B,
                    float* __restrict__ C) {
    __shared__ __align__(16) unsigned short As[4][BM][BK];
    __shared__ __align__(16) unsigned short Bs[4][BN][BK];

    // XCD-aware bijective swizzle: 512 blocks, 8 XCDs, 64 blocks/XCD
    int bid = blockIdx.x;
    int swz = (bid & 7) * 64 + (bid >> 3);
    int bm = swz >> 4;                 // 16 bn-tiles per bm-row
    int bn = swz & 15;

    int tid  = threadIdx.x;
    int wid  = tid >> 6;               // 0..7
    int lane = tid & 63;
    int wm = wid >> 2, wn = wid & 3;   // wave owns 128x64 of C

    // staging geometry (pre-swizzled global source, linear LDS dest)
    int srow  = lane >> 2;                              // 0..15
    int sslot = (lane & 3) ^ ((srow >> 1) & 3);
    const unsigned short* ag0 = A + (size_t)(bm * BM + wid * 16 + srow) * KTOT + sslot * 8;
    const unsigned short* ag1 = ag0 + (size_t)128 * KTOT;
    const unsigned short* bg0 = B + (size_t)(bn * BN + wid * 16 + srow) * KTOT + sslot * 8;
    const unsigned short* bg1 = bg0 + (size_t)128 * KTOT;

    // fragment-read geometry (same XOR on read side); rslot lane-constant
    int rl    = lane & 15;
    int rslot = (lane >> 4) ^ ((rl >> 1) & 3);

    f32x4 acc[8][4];
#pragma unroll
    for (int m = 0; m < 8; ++m)
#pragma unroll
        for (int n = 0; n < 4; ++n) acc[m][n] = (f32x4)0.f;

    auto STAGE_A = [&](int s, int k0) {
        __builtin_amdgcn_global_load_lds(
            (const __attribute__((address_space(1))) void*)(ag0 + k0),
            (__attribute__((address_space(3))) void*)&As[s][wid * 16][0], 16, 0, 0);
        __builtin_amdgcn_global_load_lds(
            (const __attribute__((address_space(1))) void*)(ag1 + k0),
            (__attribute__((address_space(3))) void*)&As[s][128 + wid * 16][0], 16, 0, 0);
    };
    auto STAGE_B = [&](int s, int k0) {
        __builtin_amdgcn_global_load_lds(
            (const __attribute__((address_space(1))) void*)(bg0 + k0),
            (__attribute__((address_space(3))) void*)&Bs[s][wid * 16][0], 16, 0, 0);
        __builtin_amdgcn_global_load_lds(
            (const __attribute__((address_space(1))) void*)(bg1 + k0),
            (__attribute__((address_space(3))) void*)&Bs[s][128 + wid * 16][0], 16, 0, 0);
    };

    auto LDA = [&](int s, int mi) -> bf16x8 {
        return *reinterpret_cast<const bf16x8*>(&As[s][wm * 128 + mi * 16 + rl][rslot * 8]);
    };
    auto LDB = [&](int s, int ni) -> bf16x8 {
        return *reinterpret_cast<const bf16x8*>(&Bs[s][wn * 64 + ni * 16 + rl][rslot * 8]);
    };

    // fragment registers: fa/fb consumed in PH0, ga consumed in PH1,
    // pa/pb = next tile's PH0 frags (prefetched in PH1)
    bf16x8 fa[4], fb[4], ga[4], pa[4], pb[4];

    // ---- prologue: stage tiles 0,1,2 (12 loads); slots 0,1 forced resident ----
    STAGE_A(0, 0);          STAGE_B(0, 0);
    STAGE_A(1, BK);         STAGE_B(1, BK);
    STAGE_A(2, 2 * BK);     STAGE_B(2, 2 * BK);
    asm volatile("s_waitcnt vmcnt(4)" ::: "memory");
    __builtin_amdgcn_s_barrier();
    // prime current frags for tile 0 PH0 (completion forced by first lgkmcnt(4))
#pragma unroll
    for (int m = 0; m < 4; ++m) fa[m] = LDA(0, m);
#pragma unroll
    for (int n = 0; n < 4; ++n) fb[n] = LDB(0, n);

    // ---- main loop: all 128 tiles; slots compile-time via x4 unroll ----
    for (int tb = 0; tb < NT; tb += 4) {
#pragma unroll
        for (int u = 0; u < 4; ++u) {
            const int t  = tb + u;
            const int s  = u;
            const int nx = (u + 1) & 3;
            const int ss = (u + 3) & 3;
            const bool st = (t + 3) < NT;
            const int k0 = (t + 3) * BK;

            // ---- PH0: prefetch ga = A(s, m4-7); stage A(t+3); MFMA m0-3 on fa,fb ----
#pragma unroll
            for (int m = 0; m < 4; ++m) ga[m] = LDA(s, m + 4);
            if (st) STAGE_A(ss, k0);
            asm volatile("s_waitcnt lgkmcnt(4)" ::: "memory");   // forces fa,fb complete
            __builtin_amdgcn_sched_barrier(0);
            __builtin_amdgcn_s_setprio(1);
#pragma unroll
            for (int m = 0; m < 4; ++m)
#pragma unroll
                for (int n = 0; n < 4; ++n)
                    acc[m][n] = __builtin_amdgcn_mfma_f32_16x16x32_bf16(fa[m], fb[n], acc[m][n], 0, 0, 0);
            __builtin_amdgcn_s_setprio(0);

            // ---- PH1: prefetch pa,pb = tile t+1 PH0 frags; stage B(t+3); MFMA m4-7 ----
#pragma unroll
            for (int m = 0; m < 4; ++m) pa[m] = LDA(nx, m);
#pragma unroll
            for (int n = 0; n < 4; ++n) pb[n] = LDB(nx, n);
            if (st) STAGE_B(ss, k0);
            asm volatile("s_waitcnt lgkmcnt(8)" ::: "memory");   // forces ga complete
            __builtin_amdgcn_sched_barrier(0);
            __builtin_amdgcn_s_setprio(1);
#pragma unroll
            for (int m = 0; m < 4; ++m)
#pragma unroll
                for (int n = 0; n < 4; ++n)
                    acc[m + 4][n] = __builtin_amdgcn_mfma_f32_16x16x32_bf16(ga[m], fb[n], acc[m + 4][n], 0, 0, 0);
            __builtin_amdgcn_s_setprio(0);

            // ---- tile end: the ONLY barrier. Forces slot (t+2)&3 resident for
            // next tile's prefetches; orders slot-s reads before restage. ----
            asm volatile("s_waitcnt vmcnt(4)" ::: "memory");
            __builtin_amdgcn_s_barrier();

            // rotate frag buffers (compiler renames; no movs after unroll)
#pragma unroll
            for (int m = 0; m < 4; ++m) fa[m] = pa[m];
#pragma unroll
            for (int n = 0; n < 4; ++n) fb[n] = pb[n];
        }
    }

    // ---- C write: per 16x16 frag, col = lane&15, row = (lane>>4)*4 + j ----
    int crow0 = bm * BM + wm * 128 + (lane >> 4) * 4;
    int ccol0 = bn * BN + wn * 64 + (lane & 15);
#pragma unroll
    for (int m = 0; m < 8; ++m)
#pragma unroll
        for (int n = 0; n < 4; ++n)
#pragma unroll
            for (int j = 0; j < 4; ++j) {
                size_t r = (size_t)(crow0 + m * 16 + j);
                size_t c = (size_t)(ccol0 + n * 16);
                C[r * NTOT + c] = acc[m][n][j];
            }
}

} // anonymous namespace

extern "C" void kernel_launch(void* const* d_in, const int* in_sizes, int n_in,
                              void* d_out, int out_size, void* d_ws, size_t ws_size,
                              hipStream_t stream) {
    const float* x = (const float*)d_in[0];   // (4,2048,4096) f32
    const float* a = (const float*)d_in[1];   // (8,8,8) f32
    const float* s = (const float*)d_in[2];   // (8,512,512) f32
    float* out = (float*)d_out;               // (4,2048,4096) f32

    unsigned short* xb = (unsigned short*)d_ws;                    // 64 MiB bf16 x
    unsigned short* wb = xb + (size_t)MTOT * KTOT;                 // 32 MiB bf16 W

    prep_kernel<<<CONV_BLOCKS + GENW_BLOCKS, 256, 0, stream>>>(x, a, s, xb, wb);
    gemm_bt_kernel<<<(MTOT / 256) * (NTOT / 256), 512, 0, stream>>>(xb, wb, out);
}